// Round 6
// baseline (43.333 us; speedup 1.0000x reference)
//
#include <hip/hip_runtime.h>

// LRP m-rule backward through AdaptiveAvgPool2d (56x56 -> 7x7, window 8x8, k=64).
//
// theta = 180deg => COS_T = -1.0 exactly, SIN_T ~ 1.2e-16. The chain collapses:
//   out_i = x_i * r / (Sx + 32*eps),  Sx = window sum (fp64: denominator can
// nearly cancel, min |denom| ~8e-7 over 401K windows). Divide in fp32.
//
// Round-6: one LANE = one full 8x8 window. 16 independent float4 loads into an
// explicit v[16] array (forces ~64 data VGPRs -> all 16 loads in flight under
// vmcnt; round-5's compiler kept VGPR=32 and exposed load latency). No
// cross-lane shuffles at all; r[wid] is a coalesced 256 B wave load.
// Consecutive lanes = consecutive windows -> each load instruction covers a
// 32 B-strided half of a contiguous band; its pair fills the other half (same
// HBM 64 B-line efficiency as before, confirmed by ideal FETCH/WRITE sizes).
//
// fp64 window sum via 4 parallel accumulators + tree merge (association change
// perturbs the denominator ~1e-15 -> absmax unchanged). Regular stores (NT
// stores doubled WRITE_SIZE in round 4 - partial-line HBM amplification).
//
// Grid: 401408 windows = 6272 waves x 64 lanes; 1568 blocks x 4 waves, no loop.

typedef float f32x4 __attribute__((ext_vector_type(4)));

static constexpr int HW     = 56 * 56;   // 3136
static constexpr int BLOCKS = 1568;      // 6272 waves total, exact cover

__global__ __launch_bounds__(256) void lrp_pool_kernel(
    const float* __restrict__ x,
    const float* __restrict__ r,
    float* __restrict__ out)
{
    const int gw   = blockIdx.x * 4 + (threadIdx.x >> 6);  // wave id 0..6271
    const int lane = threadIdx.x & 63;
    const int wid  = gw * 64 + lane;                       // window id, exact

    const int bc  = wid / 49;              // magic-mul div
    const int rem = wid - bc * 49;
    const int ohi = rem / 7;
    const int owi = rem - ohi * 7;

    const int base = bc * HW + (ohi * 8) * 56 + owi * 8;
    const float* p = x + base;

    // 16 independent 16 B loads (whole window, 256 B/lane)
    f32x4 v[16];
    #pragma unroll
    for (int rr = 0; rr < 8; ++rr) {
        v[2 * rr]     = *reinterpret_cast<const f32x4*>(p + rr * 56);
        v[2 * rr + 1] = *reinterpret_cast<const f32x4*>(p + rr * 56 + 4);
    }
    const float rv = r[wid];   // coalesced: 64 consecutive floats per wave

    // fp64 window sum: 4 parallel accumulators, then tree merge
    double a0 = 0.0, a1 = 0.0, a2 = 0.0, a3 = 0.0;
    #pragma unroll
    for (int i = 0; i < 4; ++i) {
        const f32x4 w0 = v[4 * i + 0], w1 = v[4 * i + 1];
        const f32x4 w2 = v[4 * i + 2], w3 = v[4 * i + 3];
        a0 += ((double)w0.x + (double)w0.y) + ((double)w0.z + (double)w0.w);
        a1 += ((double)w1.x + (double)w1.y) + ((double)w1.z + (double)w1.w);
        a2 += ((double)w2.x + (double)w2.y) + ((double)w2.z + (double)w2.w);
        a3 += ((double)w3.x + (double)w3.y) + ((double)w3.z + (double)w3.w);
    }
    const double s = (a0 + a1) + (a2 + a3);

    const float coef = rv / (float)(s + 32.0 * 1e-5);

    #pragma unroll
    for (int rr = 0; rr < 8; ++rr) {
        *reinterpret_cast<f32x4*>(out + base + rr * 56)     = v[2 * rr]     * coef;
        *reinterpret_cast<f32x4*>(out + base + rr * 56 + 4) = v[2 * rr + 1] * coef;
    }
}

extern "C" void kernel_launch(void* const* d_in, const int* in_sizes, int n_in,
                              void* d_out, int out_size, void* d_ws, size_t ws_size,
                              hipStream_t stream) {
    const float* x   = (const float*)d_in[0];
    const float* r   = (const float*)d_in[1];
    float*       out = (float*)d_out;
    lrp_pool_kernel<<<BLOCKS, 256, 0, stream>>>(x, r, out);
}

// Round 7
// 38.423 us; speedup vs baseline: 1.1278x; 1.1278x over previous
//
#include <hip/hip_runtime.h>

// LRP m-rule backward through AdaptiveAvgPool2d (56x56 -> 7x7, window 8x8, k=64).
//
// theta = 180deg => COS_T = -1.0 exactly, SIN_T ~ 1.2e-16. The chain collapses:
//   out_i = x_i * r / (Sx + 32*eps),  Sx = window sum (fp64: denominator can
// nearly cancel, min |denom| ~8e-7 over 401K windows). Divide in fp32.
//
// Layout (round-5, verified ideal traffic FETCH~58MB WRITE~102MB): one wave =
// 8 windows, 8-lane team per window; lane owns one full window row = 2
// contiguous float4 loads (32 B). Butterfly = 3 fp64 shuffle rounds (xor 1,2,4).
// Regular stores (NT stores amplified writes 2x in round 4; lane-per-window
// layout amplified writes 18% in round 6 -> both reverted).
//
// Round-7: explicit 2-deep software pipeline. Iteration it+1's loads (a,b,rv)
// are issued BEFORE iteration it's reduce/shuffle/divide/store, so HBM latency
// hides under the serial shuffle+divide chain (round-5's VGPR=32 showed the
// compiler never pipelined on its own; latency was fully exposed each iter).
//
// Grid: 50176 wave-groups = 7168 waves x 7 iters exact; 1792 blocks x 4 waves
// = 7 blocks/CU exact -> single resident pass, zero CU imbalance.

typedef float f32x4 __attribute__((ext_vector_type(4)));

static constexpr int HW     = 56 * 56;          // 3136
static constexpr int NWIN   = 8192 * 49;        // 401408 windows
static constexpr int NGRP   = NWIN / 8;         // 50176 wave-iterations
static constexpr int BLOCKS = 1792;             // 7 blocks/CU exact
static constexpr int WAVES  = BLOCKS * 4;       // 7168
static constexpr int NITER  = NGRP / WAVES;     // 7 (exact)

__global__ __launch_bounds__(256) void lrp_pool_kernel(
    const float* __restrict__ x,
    const float* __restrict__ r,
    float* __restrict__ out)
{
    const int tid  = threadIdx.x;
    const int lane = tid & 63;
    const int w    = lane >> 3;   // window within the wave's group of 8
    const int t    = lane & 7;    // team lane = window row

    const int g0 = blockIdx.x * 4 + (tid >> 6);

    // ---- prologue: load iteration 0 ----
    int wid = g0 * 8 + w;
    int bc  = wid / 49;
    int rem = wid - bc * 49;
    int ohi = rem / 7;
    int owi = rem - ohi * 7;
    int base = bc * HW + (ohi * 8 + t) * 56 + owi * 8;

    f32x4 a  = *reinterpret_cast<const f32x4*>(x + base);
    f32x4 b  = *reinterpret_cast<const f32x4*>(x + base + 4);
    float rv = r[wid];

    #pragma unroll
    for (int it = 0; it < NITER; ++it) {
        // ---- prefetch iteration it+1 (issued before the serial chain) ----
        f32x4 an = {}, bn = {};
        float rvn = 0.0f;
        int baseN = 0;
        if (it + 1 < NITER) {
            const int gN   = g0 + (it + 1) * WAVES;
            const int widN = gN * 8 + w;
            const int bcN  = widN / 49;
            const int remN = widN - bcN * 49;
            const int ohiN = remN / 7;
            const int owiN = remN - ohiN * 7;
            baseN = bcN * HW + (ohiN * 8 + t) * 56 + owiN * 8;
            an  = *reinterpret_cast<const f32x4*>(x + baseN);
            bn  = *reinterpret_cast<const f32x4*>(x + baseN + 4);
            rvn = r[widN];
        }

        // ---- reduce + scale current iteration ----
        double s = (((double)a.x + (double)a.y) + ((double)a.z + (double)a.w))
                 + (((double)b.x + (double)b.y) + ((double)b.z + (double)b.w));
        s += __shfl_xor(s, 1, 64);
        s += __shfl_xor(s, 2, 64);
        s += __shfl_xor(s, 4, 64);

        const float coef = rv / (float)(s + 32.0 * 1e-5);

        *reinterpret_cast<f32x4*>(out + base)     = a * coef;
        *reinterpret_cast<f32x4*>(out + base + 4) = b * coef;

        // ---- rotate pipeline registers ----
        a = an; b = bn; rv = rvn; base = baseN;
    }
}

extern "C" void kernel_launch(void* const* d_in, const int* in_sizes, int n_in,
                              void* d_out, int out_size, void* d_ws, size_t ws_size,
                              hipStream_t stream) {
    const float* x   = (const float*)d_in[0];
    const float* r   = (const float*)d_in[1];
    float*       out = (float*)d_out;
    lrp_pool_kernel<<<BLOCKS, 256, 0, stream>>>(x, r, out);
}